// Round 9
// baseline (198.025 us; speedup 1.0000x reference)
//
#include <hip/hip_runtime.h>
#include <hip/hip_bf16.h>

#define N_BOXES 8192
#define NW 128            // number of 64-box chunks / 64-bit words per row
#define FEAT 10
#define NSLOT 5           // row slots per lane; 6 worker waves * 5 = 30 rows capacity

typedef unsigned long long u64;
typedef unsigned int u32;

__device__ __forceinline__ void barrier_nodrain() {
    asm volatile("s_waitcnt lgkmcnt(0)" ::: "memory");
    __builtin_amdgcn_sched_barrier(0);
    __builtin_amdgcn_s_barrier();
    __builtin_amdgcn_sched_barrier(0);
    asm volatile("" ::: "memory");
}

// ---------------- Phase A: rank + scatter sorted boxes ----------------
// Descending-score order, ties broken by larger original index first
// (matches jnp.argsort(stable)[::-1]).
__global__ void rank_scatter_kernel(const float* __restrict__ bboxes,
                                    const float* __restrict__ scores,
                                    float* __restrict__ x1s, float* __restrict__ y1s,
                                    float* __restrict__ x2s, float* __restrict__ y2s,
                                    u32* __restrict__ rank_of) {
    __shared__ float sc[N_BOXES];
    int tid = threadIdx.x;
    for (int t = 0; t < N_BOXES / 256; ++t)
        sc[tid + 256 * t] = scores[tid + 256 * t];
    __syncthreads();
    int k = tid >> 3;          // box slot 0..31
    int s = tid & 7;           // segment 0..7
    int i = blockIdx.x * 32 + k;
    float si = sc[i];
    int cnt = 0;
    const float4* sc4 = (const float4*)sc;
    int q0 = s * (N_BOXES / 32);
    #pragma unroll 4
    for (int q = q0; q < q0 + N_BOXES / 32; ++q) {
        float4 v = sc4[q];
        int j = 4 * q;
        cnt += (int)((v.x > si) || (v.x == si && j     > i));
        cnt += (int)((v.y > si) || (v.y == si && j + 1 > i));
        cnt += (int)((v.z > si) || (v.z == si && j + 2 > i));
        cnt += (int)((v.w > si) || (v.w == si && j + 3 > i));
    }
    cnt += __shfl_down(cnt, 4, 8);
    cnt += __shfl_down(cnt, 2, 8);
    cnt += __shfl_down(cnt, 1, 8);
    if (s == 0) {
        int r = cnt;
        float x = bboxes[4 * i + 0], y = bboxes[4 * i + 1];
        float w = bboxes[4 * i + 2], h = bboxes[4 * i + 3];
        float x2 = x + w, y2 = y + h;           // exact ref op order
        x1s[r] = x; y1s[r] = y; x2s[r] = x2; y2s[r] = y2;
        rank_of[i] = (u32)r;
    }
}

// ---------------- Phase B: suppression bitmask matrix ----------------
// Row-major: RM[i*NW + cj] = word over j in chunk cj of sup(i->j) (j>i).
// TRb[d*N + j] (d=0,1,2) = word over i in chunk (chunk(j)-d) of sup(i->j).
__global__ void __launch_bounds__(256) mask_kernel(
        const float* __restrict__ x1s, const float* __restrict__ y1s,
        const float* __restrict__ x2s, const float* __restrict__ y2s,
        u64* __restrict__ RM, u64* __restrict__ TRb) {
    int wv = threadIdx.x >> 6, lane = threadIdx.x & 63;
    int ci = blockIdx.x;
    int cj = blockIdx.y * 4 + wv;
    if (cj < ci) return;
    __shared__ float S[4][4][64];
    int d = cj - ci;
    int ig0 = ci * 64, jg0 = cj * 64;
    if (d <= 2) {
        // ballot path: lanes = columns j; i-chunk staged in LDS
        S[wv][0][lane] = x1s[ig0 + lane];
        S[wv][1][lane] = y1s[ig0 + lane];
        S[wv][2][lane] = x2s[ig0 + lane];
        S[wv][3][lane] = y2s[ig0 + lane];
        int jg = jg0 + lane;
        float jx1 = x1s[jg], jy1 = y1s[jg], jx2 = x2s[jg], jy2 = y2s[jg];
        float jar = (jx2 - jx1) * (jy2 - jy1);   // bit-identical to ref area
        u64 my = 0, cw = 0;
        for (int ip = 0; ip < 64; ++ip) {
            float ax1 = S[wv][0][ip], ay1 = S[wv][1][ip];
            float ax2 = S[wv][2][ip], ay2 = S[wv][3][ip];
            float aar = (ax2 - ax1) * (ay2 - ay1);
            float xx1 = fmaxf(ax1, jx1);
            float yy1 = fmaxf(ay1, jy1);
            float xx2 = fminf(ax2, jx2);
            float yy2 = fminf(ay2, jy2);
            float iw = fmaxf(xx2 - xx1, 0.0f);
            float ih = fmaxf(yy2 - yy1, 0.0f);
            float inter = iw * ih;
            float uni = aar + jar - inter;
            float iou = __fdiv_rn(inter, uni);   // IEEE-exact like numpy
            bool sup = (iou > 0.5f) && (jg > ig0 + ip);
            u64 w = __ballot(sup);
            if (lane == ip) my = w;
            cw |= sup ? (1ull << ip) : 0ull;
        }
        RM[(size_t)(ig0 + lane) * NW + cj] = my;
        TRb[(size_t)d * N_BOXES + jg] = cw;
    } else {
        // direct path: lanes = rows i; j-chunk staged in LDS
        S[wv][0][lane] = x1s[jg0 + lane];
        S[wv][1][lane] = y1s[jg0 + lane];
        S[wv][2][lane] = x2s[jg0 + lane];
        S[wv][3][lane] = y2s[jg0 + lane];
        int ig = ig0 + lane;
        float ix1 = x1s[ig], iy1 = y1s[ig], ix2 = x2s[ig], iy2 = y2s[ig];
        float iar = (ix2 - ix1) * (iy2 - iy1);
        u64 my = 0;
        for (int jp = 0; jp < 64; ++jp) {
            float jx1 = S[wv][0][jp], jy1 = S[wv][1][jp];
            float jx2 = S[wv][2][jp], jy2 = S[wv][3][jp];
            float jar = (jx2 - jx1) * (jy2 - jy1);
            float xx1 = fmaxf(ix1, jx1);
            float yy1 = fmaxf(iy1, jy1);
            float xx2 = fminf(ix2, jx2);
            float yy2 = fminf(iy2, jy2);
            float iw = fmaxf(xx2 - xx1, 0.0f);
            float ih = fmaxf(yy2 - yy1, 0.0f);
            float inter = iw * ih;
            float uni = iar + jar - inter;
            float iou = __fdiv_rn(inter, uni);
            bool sup = (iou > 0.5f);             // cj>ci+2 => j>i always
            my |= sup ? (1ull << jp) : 0ull;
        }
        RM[(size_t)ig * NW + cj] = my;
    }
}

// ---------------- Phase C+D: greedy reduce (1 block) + fused output ---------
// No global loads on the critical wave:
//  wave0: ballot-fixpoint for chunk c; TR d0/d1 from LDS (fully preloaded),
//         TR d2 from a 4-deep LDS ring; operands prefetched 1 region ahead
//         into parity registers (LDS-only). rem32 base covers chunks <= c-3;
//         folds d1/d2 cover chunks c-1/c-2.
//  wave7: TR2 producer. At region r: ds_write ring[(r+2)&3] (global-loaded
//         2 regions earlier, vmcnt fully hidden), issue load for chunk r+4.
//  waves 1-6: grp = wv-1; rows r = s*6+grp (wave-uniform guards); lane owns
//         words bb+lane, bb+64+lane. COMMIT chunk c-2's kept rows (loaded
//         last region into H) via ds_or_b64; ISSUE chunk c-1's kept rows.
//         Overflow (kn > 30) -> immediate-load loop at commit (chunk 0 only).
__global__ void __launch_bounds__(512) nms_reduce_fused(
        const u64* __restrict__ RM, const u64* __restrict__ TRb,
        const u32* __restrict__ rank_of,
        const float* __restrict__ bboxes, const float* __restrict__ features,
        const float* __restrict__ Wm, const float* __restrict__ bv,
        const int* __restrict__ widthp, const int* __restrict__ heightp,
        float* __restrict__ out) {
    __shared__ u64 TR0L[N_BOXES];                 // 64 KiB: d0 (diag) plane
    __shared__ u64 TR1L[N_BOXES];                 // 64 KiB: d1 plane
    __shared__ u64 TR2R[4][64];                   // 2 KiB: d2 ring (wave7)
    __shared__ __align__(8) u32 rem32[NW * 2];
    __shared__ u64 keptw[NW];
    __shared__ unsigned char klist[4][64];

    const int tid = threadIdx.x;
    const int wv = tid >> 6, lane = tid & 63;
    const int grp = wv - 1;                       // 0..5 for worker waves 1..6

    // preload TR d0/d1 planes into LDS (16B-wide)
    {
        const ulonglong2* s0 = (const ulonglong2*)TRb;
        const ulonglong2* s1 = (const ulonglong2*)(TRb + N_BOXES);
        ulonglong2* d0 = (ulonglong2*)TR0L;
        ulonglong2* d1 = (ulonglong2*)TR1L;
        #pragma unroll
        for (int k2 = 0; k2 < 8; ++k2) {
            int i = tid + 512 * k2;
            d0[i] = s0[i];
            d1[i] = s1[i];
        }
    }
    if (tid < NW * 2) rem32[tid] = 0;

    const u64* TRb2 = TRb + 2 * N_BOXES;
    u64 trA = 0, trB = 0;                         // wave7 pipeline regs
    if (wv == 7) { trA = TRb2[2 * 64 + lane]; trB = TRb2[3 * 64 + lane]; }
    __syncthreads();

    // wave0 state
    u64 kp1 = 0, kp2 = 0;
    u64 TDr[2], T1r[2], T2r[2];
    if (wv == 0) {
        TDr[0] = TR0L[lane];                      // chunk 0 d0
        T1r[0] = TR1L[lane];                      // chunk 0 d1 (garbage, kp1=0)
        T2r[0] = TR2R[0][lane];                   // chunk 0 d2 (garbage, kp2=0)
    }
    // worker state
    u64 H0[2][NSLOT], H1[2][NSLOT];
    u32 Kn[2] = {0, 0};

#define REGION(RC, PAR, TRREG)                                                  \
  do {                                                                          \
    const int c_ = (RC);                                                        \
    if (wv == 0) {                                                              \
      u64 TD = TDr[PAR], T1f = T1r[PAR], T2f = T2r[PAR];                        \
      u64 base = *(const u64*)&rem32[2 * c_];                                   \
      u64 R = base | __ballot(((T1f & kp1) | (T2f & kp2)) != 0ull);             \
      u64 K = 0, U = ~R;                                                        \
      bool meU = (U >> lane) & 1;                                               \
      while (U) {                                                               \
        u64 UK = U | K;                                                         \
        u64 nK = __ballot(meU && ((TD & UK) == 0ull));                          \
        K |= nK;                                                                \
        u64 nR = __ballot(meU && ((TD & K) != 0ull));                           \
        U &= ~(K | nR);                                                         \
        meU = (U >> lane) & 1;                                                  \
      }                                                                         \
      bool isk = (K >> lane) & 1;                                               \
      int rnk = __popcll(K & ((1ull << lane) - 1ull));                          \
      if (isk) klist[c_ & 3][rnk] = (unsigned char)lane;                        \
      if (lane == 0) keptw[c_] = K;                                             \
      kp2 = kp1; kp1 = K;                                                       \
      {                                                                         \
        const int cn = (c_ + 1 < NW) ? c_ + 1 : c_;  /* clamped prefetch */     \
        TDr[PAR ^ 1] = TR0L[cn * 64 + lane];                                    \
        T1r[PAR ^ 1] = TR1L[cn * 64 + lane];                                    \
        T2r[PAR ^ 1] = TR2R[cn & 3][lane];                                      \
      }                                                                         \
    } else if (wv == 7) {                                                       \
      if (c_ + 2 < NW) TR2R[(c_ + 2) & 3][lane] = TRREG;                        \
      if (c_ + 4 < NW) TRREG = TRb2[(c_ + 4) * 64 + lane];                      \
    } else {                                                                    \
      /* COMMIT chunk c_-2 (slots loaded last region); words bb=c_+1 */         \
      if (c_ >= 2 && Kn[PAR] > 0) {                                             \
        const int wd0 = c_ + 1 + lane;                                          \
        const int wd1 = wd0 + 64;                                               \
        u64 v0 = 0, v1 = 0;                                                     \
        _Pragma("unroll")                                                       \
        for (int s = 0; s < NSLOT; ++s) { v0 |= H0[PAR][s]; v1 |= H1[PAR][s]; } \
        u32 kn = Kn[PAR];                                                       \
        if (kn > 6u * NSLOT) {                     /* rare overflow */          \
          const u32 cpb = (u32)(c_ - 2) * 64u;                                  \
          const unsigned char* kl = klist[(c_ + 2) & 3];                        \
          for (u32 r = 6u * NSLOT + (u32)grp; r < kn; r += 6u) {                \
            const u64* rp = RM + (size_t)(cpb + kl[r]) * NW;                    \
            if (wd0 < NW) v0 |= rp[wd0];                                        \
            if (wd1 < NW) v1 |= rp[wd1];                                        \
          }                                                                     \
        }                                                                       \
        if (wd0 < NW && v0) atomicOr((u64*)&rem32[2 * wd0], v0);                \
        if (wd1 < NW && v1) atomicOr((u64*)&rem32[2 * wd1], v1);                \
      }                                                                         \
      /* ISSUE chunk c_-1 (consumed next region); words bb=c_+2 */              \
      {                                                                         \
        const int NP = PAR ^ 1;                                                 \
        const int cp = c_ - 1;                                                  \
        if (cp >= 0 && cp + 3 < NW) {                                           \
          u64 KW = keptw[cp];                                                   \
          u32 kn = (u32)__popcll(KW);                                           \
          Kn[NP] = kn;                                                          \
          const int wi0 = c_ + 2 + lane;                                        \
          const int wi1 = wi0 + 64;                                             \
          const unsigned char* kl = klist[cp & 3];                              \
          const u32 cpb = (u32)cp * 64u;                                        \
          _Pragma("unroll")                                                     \
          for (int s = 0; s < NSLOT; ++s) {                                     \
            H0[NP][s] = 0; H1[NP][s] = 0;                                       \
            u32 r = (u32)(s * 6 + grp);            /* wave-uniform */           \
            if (r < kn) {                                                       \
              const u64* rp = RM + (size_t)(cpb + kl[r]) * NW;                  \
              if (wi0 < NW) H0[NP][s] = rp[wi0];                                \
              if (wi1 < NW) H1[NP][s] = rp[wi1];                                \
            }                                                                   \
          }                                                                     \
        } else Kn[NP] = 0;                                                      \
      }                                                                         \
    }                                                                           \
    barrier_nodrain();                                                          \
  } while (0)

    for (int cc = 0; cc < NW; cc += 2) {
        REGION(cc, 0, trA);
        REGION(cc + 1, 1, trB);
    }
#undef REGION

    __syncthreads();

    // ---------------- fused output tail ----------------
    float wreg[FEAT * 4];
    #pragma unroll
    for (int m = 0; m < FEAT * 4; ++m) wreg[m] = Wm[m];
    float bb0 = bv[0], bb1 = bv[1], bb2 = bv[2], bb3 = bv[3];
    float sw = (float)(*widthp), sh = (float)(*heightp);
    for (int k = 0; k < N_BOXES / 512; ++k) {
        int i = tid + 512 * k;
        u32 r = rank_of[i];
        float keep = (float)((keptw[r >> 6] >> (r & 63)) & 1ull);
        float z0 = bb0, z1 = bb1, z2 = bb2, z3 = bb3;
        #pragma unroll
        for (int m = 0; m < FEAT; ++m) {
            float f = features[i * FEAT + m];
            z0 += f * wreg[m * 4 + 0];
            z1 += f * wreg[m * 4 + 1];
            z2 += f * wreg[m * 4 + 2];
            z3 += f * wreg[m * 4 + 3];
        }
        float t0 = 1.0f / (1.0f + expf(-z0));
        float t1 = 1.0f / (1.0f + expf(-z1));
        float t2 = 1.0f / (1.0f + expf(-z2));
        float t3 = 1.0f / (1.0f + expf(-z3));
        float4 bx = ((const float4*)bboxes)[i];
        float ox = fmaxf(t0 * bx.z + bx.x, 0.0f);
        float oy = fmaxf(t1 * bx.w + bx.y, 0.0f);
        float ow = bx.z * expf(t2);
        float oh = bx.w * expf(t3);
        float4 o;
        o.x = ox * sw * keep;
        o.y = oy * sh * keep;
        o.z = ow * sw * keep;
        o.w = oh * sh * keep;
        ((float4*)out)[i] = o;
    }
}

extern "C" void kernel_launch(void* const* d_in, const int* in_sizes, int n_in,
                              void* d_out, int out_size, void* d_ws, size_t ws_size,
                              hipStream_t stream) {
    const float* bboxes   = (const float*)d_in[0];
    const float* scores   = (const float*)d_in[1];
    const float* features = (const float*)d_in[2];
    const float* Wm       = (const float*)d_in[3];
    const float* bv       = (const float*)d_in[4];
    const int*   widthp   = (const int*)d_in[5];
    const int*   heightp  = (const int*)d_in[6];
    float* out = (float*)d_out;

    char* ws = (char*)d_ws;
    u64* RM      = (u64*)ws;                                        // 8 MiB
    u64* TRb     = (u64*)(ws + (size_t)N_BOXES * NW * sizeof(u64)); // 192 KiB
    float* x1s   = (float*)((char*)TRb + (size_t)3 * N_BOXES * sizeof(u64));
    float* y1s   = x1s + N_BOXES;
    float* x2s   = y1s + N_BOXES;
    float* y2s   = x2s + N_BOXES;
    u32* rank_of = (u32*)(y2s + N_BOXES);

    rank_scatter_kernel<<<N_BOXES / 32, 256, 0, stream>>>(bboxes, scores,
                                                          x1s, y1s, x2s, y2s, rank_of);
    mask_kernel<<<dim3(NW, NW / 4), 256, 0, stream>>>(x1s, y1s, x2s, y2s, RM, TRb);
    nms_reduce_fused<<<1, 512, 0, stream>>>(RM, TRb, rank_of, bboxes, features,
                                            Wm, bv, widthp, heightp, out);
}

// Round 10
// 164.030 us; speedup vs baseline: 1.2072x; 1.2072x over previous
//
#include <hip/hip_runtime.h>
#include <hip/hip_bf16.h>

#define N_BOXES 8192
#define NW 128            // number of 64-box chunks / 64-bit words per row
#define FEAT 10
#define NSLOT 4           // row slots per lane; 7 worker waves * 4 = 28 rows capacity

typedef unsigned long long u64;
typedef unsigned int u32;

__device__ __forceinline__ void barrier_nodrain() {
    asm volatile("s_waitcnt lgkmcnt(0)" ::: "memory");
    __builtin_amdgcn_sched_barrier(0);
    __builtin_amdgcn_s_barrier();
    __builtin_amdgcn_sched_barrier(0);
    asm volatile("" ::: "memory");
}

// ---------------- Phase A: rank + scatter sorted boxes ----------------
// Descending-score order, ties broken by larger original index first
// (matches jnp.argsort(stable)[::-1]).
__global__ void rank_scatter_kernel(const float* __restrict__ bboxes,
                                    const float* __restrict__ scores,
                                    float* __restrict__ x1s, float* __restrict__ y1s,
                                    float* __restrict__ x2s, float* __restrict__ y2s,
                                    u32* __restrict__ rank_of) {
    __shared__ float sc[N_BOXES];
    int tid = threadIdx.x;
    for (int t = 0; t < N_BOXES / 256; ++t)
        sc[tid + 256 * t] = scores[tid + 256 * t];
    __syncthreads();
    int k = tid >> 3;          // box slot 0..31
    int s = tid & 7;           // segment 0..7
    int i = blockIdx.x * 32 + k;
    float si = sc[i];
    int cnt = 0;
    const float4* sc4 = (const float4*)sc;
    int q0 = s * (N_BOXES / 32);
    #pragma unroll 4
    for (int q = q0; q < q0 + N_BOXES / 32; ++q) {
        float4 v = sc4[q];
        int j = 4 * q;
        cnt += (int)((v.x > si) || (v.x == si && j     > i));
        cnt += (int)((v.y > si) || (v.y == si && j + 1 > i));
        cnt += (int)((v.z > si) || (v.z == si && j + 2 > i));
        cnt += (int)((v.w > si) || (v.w == si && j + 3 > i));
    }
    cnt += __shfl_down(cnt, 4, 8);
    cnt += __shfl_down(cnt, 2, 8);
    cnt += __shfl_down(cnt, 1, 8);
    if (s == 0) {
        int r = cnt;
        float x = bboxes[4 * i + 0], y = bboxes[4 * i + 1];
        float w = bboxes[4 * i + 2], h = bboxes[4 * i + 3];
        float x2 = x + w, y2 = y + h;           // exact ref op order
        x1s[r] = x; y1s[r] = y; x2s[r] = x2; y2s[r] = y2;
        rank_of[i] = (u32)r;
    }
}

// ---------------- Phase B: suppression bitmask matrix ----------------
// Row-major: RM[i*NW + cj] = word over j in chunk cj of sup(i->j) (j>i).
// TRb[d*N + j] (d=0..3) = word over i in chunk (chunk(j)-d) of sup(i->j).
__global__ void __launch_bounds__(256) mask_kernel(
        const float* __restrict__ x1s, const float* __restrict__ y1s,
        const float* __restrict__ x2s, const float* __restrict__ y2s,
        u64* __restrict__ RM, u64* __restrict__ TRb) {
    int wv = threadIdx.x >> 6, lane = threadIdx.x & 63;
    int ci = blockIdx.x;
    int cj = blockIdx.y * 4 + wv;
    if (cj < ci) return;
    __shared__ float S[4][4][64];
    int d = cj - ci;
    int ig0 = ci * 64, jg0 = cj * 64;
    if (d <= 3) {
        // ballot path: lanes = columns j; i-chunk staged in LDS
        S[wv][0][lane] = x1s[ig0 + lane];
        S[wv][1][lane] = y1s[ig0 + lane];
        S[wv][2][lane] = x2s[ig0 + lane];
        S[wv][3][lane] = y2s[ig0 + lane];
        int jg = jg0 + lane;
        float jx1 = x1s[jg], jy1 = y1s[jg], jx2 = x2s[jg], jy2 = y2s[jg];
        float jar = (jx2 - jx1) * (jy2 - jy1);   // bit-identical to ref area
        u64 my = 0, cw = 0;
        for (int ip = 0; ip < 64; ++ip) {
            float ax1 = S[wv][0][ip], ay1 = S[wv][1][ip];
            float ax2 = S[wv][2][ip], ay2 = S[wv][3][ip];
            float aar = (ax2 - ax1) * (ay2 - ay1);
            float xx1 = fmaxf(ax1, jx1);
            float yy1 = fmaxf(ay1, jy1);
            float xx2 = fminf(ax2, jx2);
            float yy2 = fminf(ay2, jy2);
            float iw = fmaxf(xx2 - xx1, 0.0f);
            float ih = fmaxf(yy2 - yy1, 0.0f);
            float inter = iw * ih;
            float uni = aar + jar - inter;
            float iou = __fdiv_rn(inter, uni);   // IEEE-exact like numpy
            bool sup = (iou > 0.5f) && (jg > ig0 + ip);
            u64 w = __ballot(sup);
            if (lane == ip) my = w;
            cw |= sup ? (1ull << ip) : 0ull;
        }
        RM[(size_t)(ig0 + lane) * NW + cj] = my;
        TRb[(size_t)d * N_BOXES + jg] = cw;
    } else {
        // direct path: lanes = rows i; j-chunk staged in LDS
        S[wv][0][lane] = x1s[jg0 + lane];
        S[wv][1][lane] = y1s[jg0 + lane];
        S[wv][2][lane] = x2s[jg0 + lane];
        S[wv][3][lane] = y2s[jg0 + lane];
        int ig = ig0 + lane;
        float ix1 = x1s[ig], iy1 = y1s[ig], ix2 = x2s[ig], iy2 = y2s[ig];
        float iar = (ix2 - ix1) * (iy2 - iy1);
        u64 my = 0;
        for (int jp = 0; jp < 64; ++jp) {
            float jx1 = S[wv][0][jp], jy1 = S[wv][1][jp];
            float jx2 = S[wv][2][jp], jy2 = S[wv][3][jp];
            float jar = (jx2 - jx1) * (jy2 - jy1);
            float xx1 = fmaxf(ix1, jx1);
            float yy1 = fmaxf(iy1, jy1);
            float xx2 = fminf(ix2, jx2);
            float yy2 = fminf(iy2, jy2);
            float iw = fmaxf(xx2 - xx1, 0.0f);
            float ih = fmaxf(yy2 - yy1, 0.0f);
            float inter = iw * ih;
            float uni = iar + jar - inter;
            float iou = __fdiv_rn(inter, uni);
            bool sup = (iou > 0.5f);             // cj>ci+3 => j>i always
            my |= sup ? (1ull << jp) : 0ull;
        }
        RM[(size_t)ig * NW + cj] = my;
    }
}

// ---------------- Phase C+D: greedy reduce (1 block) + fused output ---------
// Push-kept, 2-region worker flight (R8 structure + deeper pipeline):
//  wave0: ballot-fixpoint for chunk c (rem32 base = kept chunks <= c-4;
//         register folds d1/d2/d3 cover chunks c-1/c-2/c-3 via TR planes
//         global-prefetched 2 regions ahead into parity regs).
//  waves 1-7: grp = wv-1 (0..6); lane owns words bb+lane, bb+64+lane.
//         COMMIT chunk c-3's kept rows (loads issued at region c-2, ~2
//         regions of flight hides HBM latency) into words >= c+1 via
//         ds_or_b64; then ISSUE chunk c-1's kept rows (words >= c+3).
//         H/Kn indexed [PAR]: commit-before-issue gives period-2 reuse.
//         Overflow (kn > 28) -> immediate-load loop at commit (chunk 0 only).
__global__ void __launch_bounds__(512) nms_reduce_fused(
        const u64* __restrict__ RM, const u64* __restrict__ TRb,
        const u32* __restrict__ rank_of,
        const float* __restrict__ bboxes, const float* __restrict__ features,
        const float* __restrict__ Wm, const float* __restrict__ bv,
        const int* __restrict__ widthp, const int* __restrict__ heightp,
        float* __restrict__ out) {
    __shared__ __align__(8) u32 rem32[NW * 2];
    __shared__ u64 keptw[NW];
    __shared__ unsigned char klist[4][64];

    const int tid = threadIdx.x;
    const int wv = tid >> 6, lane = tid & 63;
    const int grp = wv - 1;                       // 0..6 for workers

    if (tid < NW * 2) rem32[tid] = 0;

    u64 TR0[2], TR1[2], TR2[2], TR3[2];
    u64 kp1 = 0, kp2 = 0, kp3 = 0;
    if (wv == 0) {
        TR0[0] = TRb[lane];
        TR1[0] = TRb[N_BOXES + lane];             // chunk0 d1: garbage, kp1=0
        TR2[0] = TRb[2 * N_BOXES + lane];         // chunk0 d2: garbage, kp2=0
        TR3[0] = TRb[3 * N_BOXES + lane];         // chunk0 d3: garbage, kp3=0
        TR0[1] = TRb[64 + lane];
        TR1[1] = TRb[N_BOXES + 64 + lane];
        TR2[1] = TRb[2 * N_BOXES + 64 + lane];    // chunk1 d2: garbage, kp2=0
        TR3[1] = TRb[3 * N_BOXES + 64 + lane];    // chunk1 d3: garbage, kp3=0
    }
    u64 H0[2][NSLOT], H1[2][NSLOT];
    u32 Kn[2] = {0, 0};
    __syncthreads();

#define REGION(RC, PAR)                                                         \
  do {                                                                          \
    const int c_ = (RC);                                                        \
    if (wv == 0) {                                                              \
      u64 TD = TR0[PAR], T1f = TR1[PAR], T2f = TR2[PAR], T3f = TR3[PAR];        \
      u64 base = *(const u64*)&rem32[2 * c_];                                   \
      u64 R = base |                                                            \
              __ballot(((T1f & kp1) | (T2f & kp2) | (T3f & kp3)) != 0ull);      \
      u64 K = 0, U = ~R;                                                        \
      bool meU = (U >> lane) & 1;                                               \
      while (U) {                                                               \
        u64 UK = U | K;                                                         \
        u64 nK = __ballot(meU && ((TD & UK) == 0ull));                          \
        K |= nK;                                                                \
        u64 nR = __ballot(meU && ((TD & K) != 0ull));                           \
        U &= ~(K | nR);                                                         \
        meU = (U >> lane) & 1;                                                  \
      }                                                                         \
      bool isk = (K >> lane) & 1;                                               \
      int rnk = __popcll(K & ((1ull << lane) - 1ull));                          \
      if (isk) klist[c_ & 3][rnk] = (unsigned char)lane;                        \
      if (lane == 0) keptw[c_] = K;                                             \
      kp3 = kp2; kp2 = kp1; kp1 = K;                                            \
      if (c_ + 2 < NW) {                                                        \
        TR0[PAR] = TRb[(c_ + 2) * 64 + lane];                                   \
        TR1[PAR] = TRb[N_BOXES + (c_ + 2) * 64 + lane];                         \
        TR2[PAR] = TRb[2 * N_BOXES + (c_ + 2) * 64 + lane];                     \
        TR3[PAR] = TRb[3 * N_BOXES + (c_ + 2) * 64 + lane];                     \
      }                                                                         \
    } else {                                                                    \
      /* COMMIT chunk c_-3 (loads issued region c_-2); words bb=c_+1 */         \
      if (c_ >= 3 && Kn[PAR] > 0) {                                             \
        const int wd0 = c_ + 1 + lane;                                          \
        const int wd1 = wd0 + 64;                                               \
        u64 v0 = 0, v1 = 0;                                                     \
        _Pragma("unroll")                                                       \
        for (int s = 0; s < NSLOT; ++s) { v0 |= H0[PAR][s]; v1 |= H1[PAR][s]; } \
        u32 kn = Kn[PAR];                                                       \
        if (kn > 7u * NSLOT) {                     /* rare overflow */          \
          const u32 cpb = (u32)(c_ - 3) * 64u;                                  \
          const unsigned char* kl = klist[(c_ + 1) & 3];                        \
          for (u32 r = 7u * NSLOT + (u32)grp; r < kn; r += 7u) {                \
            const u64* rp = RM + (size_t)(cpb + kl[r]) * NW;                    \
            if (wd0 < NW) v0 |= rp[wd0];                                        \
            if (wd1 < NW) v1 |= rp[wd1];                                        \
          }                                                                     \
        }                                                                       \
        if (wd0 < NW && v0) atomicOr((u64*)&rem32[2 * wd0], v0);                \
        if (wd1 < NW && v1) atomicOr((u64*)&rem32[2 * wd1], v1);                \
      }                                                                         \
      /* ISSUE chunk c_-1 (committed at region c_+2); words bb=c_+3 */          \
      {                                                                         \
        const int cp = c_ - 1;                                                  \
        if (cp >= 0 && c_ + 3 < NW) {                                           \
          u64 KW = keptw[cp];                                                   \
          u32 kn = (u32)__popcll(KW);                                           \
          Kn[PAR] = kn;                                                         \
          const int wi0 = c_ + 3 + lane;                                        \
          const int wi1 = wi0 + 64;                                             \
          const unsigned char* kl = klist[cp & 3];                              \
          const u32 cpb = (u32)cp * 64u;                                        \
          _Pragma("unroll")                                                     \
          for (int s = 0; s < NSLOT; ++s) {                                     \
            H0[PAR][s] = 0; H1[PAR][s] = 0;                                     \
            u32 r = (u32)(s * 7 + grp);            /* wave-uniform */           \
            if (r < kn) {                                                       \
              const u64* rp = RM + (size_t)(cpb + kl[r]) * NW;                  \
              if (wi0 < NW) H0[PAR][s] = rp[wi0];                               \
              if (wi1 < NW) H1[PAR][s] = rp[wi1];                               \
            }                                                                   \
          }                                                                     \
        } else Kn[PAR] = 0;                                                     \
      }                                                                         \
    }                                                                           \
    barrier_nodrain();                                                          \
  } while (0)

    for (int cc = 0; cc < NW; cc += 2) {
        REGION(cc, 0);
        REGION(cc + 1, 1);
    }
#undef REGION

    __syncthreads();

    // ---------------- fused output tail ----------------
    float wreg[FEAT * 4];
    #pragma unroll
    for (int m = 0; m < FEAT * 4; ++m) wreg[m] = Wm[m];
    float bb0 = bv[0], bb1 = bv[1], bb2 = bv[2], bb3 = bv[3];
    float sw = (float)(*widthp), sh = (float)(*heightp);
    for (int k = 0; k < N_BOXES / 512; ++k) {
        int i = tid + 512 * k;
        u32 r = rank_of[i];
        float keep = (float)((keptw[r >> 6] >> (r & 63)) & 1ull);
        float z0 = bb0, z1 = bb1, z2 = bb2, z3 = bb3;
        #pragma unroll
        for (int m = 0; m < FEAT; ++m) {
            float f = features[i * FEAT + m];
            z0 += f * wreg[m * 4 + 0];
            z1 += f * wreg[m * 4 + 1];
            z2 += f * wreg[m * 4 + 2];
            z3 += f * wreg[m * 4 + 3];
        }
        float t0 = 1.0f / (1.0f + expf(-z0));
        float t1 = 1.0f / (1.0f + expf(-z1));
        float t2 = 1.0f / (1.0f + expf(-z2));
        float t3 = 1.0f / (1.0f + expf(-z3));
        float4 bx = ((const float4*)bboxes)[i];
        float ox = fmaxf(t0 * bx.z + bx.x, 0.0f);
        float oy = fmaxf(t1 * bx.w + bx.y, 0.0f);
        float ow = bx.z * expf(t2);
        float oh = bx.w * expf(t3);
        float4 o;
        o.x = ox * sw * keep;
        o.y = oy * sh * keep;
        o.z = ow * sw * keep;
        o.w = oh * sh * keep;
        ((float4*)out)[i] = o;
    }
}

extern "C" void kernel_launch(void* const* d_in, const int* in_sizes, int n_in,
                              void* d_out, int out_size, void* d_ws, size_t ws_size,
                              hipStream_t stream) {
    const float* bboxes   = (const float*)d_in[0];
    const float* scores   = (const float*)d_in[1];
    const float* features = (const float*)d_in[2];
    const float* Wm       = (const float*)d_in[3];
    const float* bv       = (const float*)d_in[4];
    const int*   widthp   = (const int*)d_in[5];
    const int*   heightp  = (const int*)d_in[6];
    float* out = (float*)d_out;

    char* ws = (char*)d_ws;
    u64* RM      = (u64*)ws;                                        // 8 MiB
    u64* TRb     = (u64*)(ws + (size_t)N_BOXES * NW * sizeof(u64)); // 256 KiB
    float* x1s   = (float*)((char*)TRb + (size_t)4 * N_BOXES * sizeof(u64));
    float* y1s   = x1s + N_BOXES;
    float* x2s   = y1s + N_BOXES;
    float* y2s   = x2s + N_BOXES;
    u32* rank_of = (u32*)(y2s + N_BOXES);

    rank_scatter_kernel<<<N_BOXES / 32, 256, 0, stream>>>(bboxes, scores,
                                                          x1s, y1s, x2s, y2s, rank_of);
    mask_kernel<<<dim3(NW, NW / 4), 256, 0, stream>>>(x1s, y1s, x2s, y2s, RM, TRb);
    nms_reduce_fused<<<1, 512, 0, stream>>>(RM, TRb, rank_of, bboxes, features,
                                            Wm, bv, widthp, heightp, out);
}

// Round 11
// 151.430 us; speedup vs baseline: 1.3077x; 1.0832x over previous
//
#include <hip/hip_runtime.h>
#include <hip/hip_bf16.h>

#define N_BOXES 8192
#define NW 128            // number of 64-box chunks / 64-bit words per row
#define FEAT 10
#define NSLOT 4           // row slots per lane; 7 worker waves * 4 = 28 rows capacity

typedef unsigned long long u64;
typedef unsigned int u32;

__device__ __forceinline__ void barrier_nodrain() {
    asm volatile("s_waitcnt lgkmcnt(0)" ::: "memory");
    __builtin_amdgcn_sched_barrier(0);
    __builtin_amdgcn_s_barrier();
    __builtin_amdgcn_sched_barrier(0);
    asm volatile("" ::: "memory");
}

// ---------------- Phase A: rank + scatter sorted boxes ----------------
// Descending-score order, ties broken by larger original index first
// (matches jnp.argsort(stable)[::-1]).
__global__ void rank_scatter_kernel(const float* __restrict__ bboxes,
                                    const float* __restrict__ scores,
                                    float* __restrict__ x1s, float* __restrict__ y1s,
                                    float* __restrict__ x2s, float* __restrict__ y2s,
                                    u32* __restrict__ rank_of) {
    __shared__ float sc[N_BOXES];
    int tid = threadIdx.x;
    for (int t = 0; t < N_BOXES / 256; ++t)
        sc[tid + 256 * t] = scores[tid + 256 * t];
    __syncthreads();
    int k = tid >> 3;          // box slot 0..31
    int s = tid & 7;           // segment 0..7
    int i = blockIdx.x * 32 + k;
    float si = sc[i];
    int cnt = 0;
    const float4* sc4 = (const float4*)sc;
    int q0 = s * (N_BOXES / 32);
    #pragma unroll 4
    for (int q = q0; q < q0 + N_BOXES / 32; ++q) {
        float4 v = sc4[q];
        int j = 4 * q;
        cnt += (int)((v.x > si) || (v.x == si && j     > i));
        cnt += (int)((v.y > si) || (v.y == si && j + 1 > i));
        cnt += (int)((v.z > si) || (v.z == si && j + 2 > i));
        cnt += (int)((v.w > si) || (v.w == si && j + 3 > i));
    }
    cnt += __shfl_down(cnt, 4, 8);
    cnt += __shfl_down(cnt, 2, 8);
    cnt += __shfl_down(cnt, 1, 8);
    if (s == 0) {
        int r = cnt;
        float x = bboxes[4 * i + 0], y = bboxes[4 * i + 1];
        float w = bboxes[4 * i + 2], h = bboxes[4 * i + 3];
        float x2 = x + w, y2 = y + h;           // exact ref op order
        x1s[r] = x; y1s[r] = y; x2s[r] = x2; y2s[r] = y2;
        rank_of[i] = (u32)r;
    }
}

// ---------------- Phase B: suppression bitmask matrix ----------------
// Row-major: RM[i*NW + cj] = word over j in chunk cj of sup(i->j) (j>i).
// TRb[d*N + j] (d=0..3) = word over i in chunk (chunk(j)-d) of sup(i->j).
__global__ void __launch_bounds__(256) mask_kernel(
        const float* __restrict__ x1s, const float* __restrict__ y1s,
        const float* __restrict__ x2s, const float* __restrict__ y2s,
        u64* __restrict__ RM, u64* __restrict__ TRb) {
    int wv = threadIdx.x >> 6, lane = threadIdx.x & 63;
    int ci = blockIdx.x;
    int cj = blockIdx.y * 4 + wv;
    if (cj < ci) return;
    __shared__ float S[4][4][64];
    int d = cj - ci;
    int ig0 = ci * 64, jg0 = cj * 64;
    if (d <= 3) {
        // ballot path: lanes = columns j; i-chunk staged in LDS
        S[wv][0][lane] = x1s[ig0 + lane];
        S[wv][1][lane] = y1s[ig0 + lane];
        S[wv][2][lane] = x2s[ig0 + lane];
        S[wv][3][lane] = y2s[ig0 + lane];
        int jg = jg0 + lane;
        float jx1 = x1s[jg], jy1 = y1s[jg], jx2 = x2s[jg], jy2 = y2s[jg];
        float jar = (jx2 - jx1) * (jy2 - jy1);   // bit-identical to ref area
        u64 my = 0, cw = 0;
        for (int ip = 0; ip < 64; ++ip) {
            float ax1 = S[wv][0][ip], ay1 = S[wv][1][ip];
            float ax2 = S[wv][2][ip], ay2 = S[wv][3][ip];
            float aar = (ax2 - ax1) * (ay2 - ay1);
            float xx1 = fmaxf(ax1, jx1);
            float yy1 = fmaxf(ay1, jy1);
            float xx2 = fminf(ax2, jx2);
            float yy2 = fminf(ay2, jy2);
            float iw = fmaxf(xx2 - xx1, 0.0f);
            float ih = fmaxf(yy2 - yy1, 0.0f);
            float inter = iw * ih;
            float uni = aar + jar - inter;
            float iou = __fdiv_rn(inter, uni);   // IEEE-exact like numpy
            bool sup = (iou > 0.5f) && (jg > ig0 + ip);
            u64 w = __ballot(sup);
            if (lane == ip) my = w;
            cw |= sup ? (1ull << ip) : 0ull;
        }
        RM[(size_t)(ig0 + lane) * NW + cj] = my;
        TRb[(size_t)d * N_BOXES + jg] = cw;
    } else {
        // direct path: lanes = rows i; j-chunk staged in LDS
        S[wv][0][lane] = x1s[jg0 + lane];
        S[wv][1][lane] = y1s[jg0 + lane];
        S[wv][2][lane] = x2s[jg0 + lane];
        S[wv][3][lane] = y2s[jg0 + lane];
        int ig = ig0 + lane;
        float ix1 = x1s[ig], iy1 = y1s[ig], ix2 = x2s[ig], iy2 = y2s[ig];
        float iar = (ix2 - ix1) * (iy2 - iy1);
        u64 my = 0;
        for (int jp = 0; jp < 64; ++jp) {
            float jx1 = S[wv][0][jp], jy1 = S[wv][1][jp];
            float jx2 = S[wv][2][jp], jy2 = S[wv][3][jp];
            float jar = (jx2 - jx1) * (jy2 - jy1);
            float xx1 = fmaxf(ix1, jx1);
            float yy1 = fmaxf(iy1, jy1);
            float xx2 = fminf(ix2, jx2);
            float yy2 = fminf(iy2, jy2);
            float iw = fmaxf(xx2 - xx1, 0.0f);
            float ih = fmaxf(yy2 - yy1, 0.0f);
            float inter = iw * ih;
            float uni = iar + jar - inter;
            float iou = __fdiv_rn(inter, uni);
            bool sup = (iou > 0.5f);             // cj>ci+3 => j>i always
            my |= sup ? (1ull << jp) : 0ull;
        }
        RM[(size_t)ig * NW + cj] = my;
    }
}

// ---------------- Phase C: greedy reduce (1 block) ----------------
// Push-kept, 2-region worker flight (identical loop to round 10, which
// passed). Output tail DE-FUSED into a full-grid kernel: the tail's ~480 KB
// of cold HBM reads through one CU was ~30% of this kernel's time.
__global__ void __launch_bounds__(512) nms_reduce_fused(
        const u64* __restrict__ RM, const u64* __restrict__ TRb,
        u64* __restrict__ keepw_g) {
    __shared__ __align__(8) u32 rem32[NW * 2];
    __shared__ u64 keptw[NW];
    __shared__ unsigned char klist[4][64];

    const int tid = threadIdx.x;
    const int wv = tid >> 6, lane = tid & 63;
    const int grp = wv - 1;                       // 0..6 for workers

    if (tid < NW * 2) rem32[tid] = 0;

    u64 TR0[2], TR1[2], TR2[2], TR3[2];
    u64 kp1 = 0, kp2 = 0, kp3 = 0;
    if (wv == 0) {
        TR0[0] = TRb[lane];
        TR1[0] = TRb[N_BOXES + lane];             // chunk0 d1: garbage, kp1=0
        TR2[0] = TRb[2 * N_BOXES + lane];         // chunk0 d2: garbage, kp2=0
        TR3[0] = TRb[3 * N_BOXES + lane];         // chunk0 d3: garbage, kp3=0
        TR0[1] = TRb[64 + lane];
        TR1[1] = TRb[N_BOXES + 64 + lane];
        TR2[1] = TRb[2 * N_BOXES + 64 + lane];    // chunk1 d2: garbage, kp2=0
        TR3[1] = TRb[3 * N_BOXES + 64 + lane];    // chunk1 d3: garbage, kp3=0
    }
    u64 H0[2][NSLOT], H1[2][NSLOT];
    u32 Kn[2] = {0, 0};
    __syncthreads();

#define REGION(RC, PAR)                                                         \
  do {                                                                          \
    const int c_ = (RC);                                                        \
    if (wv == 0) {                                                              \
      u64 TD = TR0[PAR], T1f = TR1[PAR], T2f = TR2[PAR], T3f = TR3[PAR];        \
      u64 base = *(const u64*)&rem32[2 * c_];                                   \
      u64 R = base |                                                            \
              __ballot(((T1f & kp1) | (T2f & kp2) | (T3f & kp3)) != 0ull);      \
      u64 K = 0, U = ~R;                                                        \
      bool meU = (U >> lane) & 1;                                               \
      while (U) {                                                               \
        u64 UK = U | K;                                                         \
        u64 nK = __ballot(meU && ((TD & UK) == 0ull));                          \
        K |= nK;                                                                \
        u64 nR = __ballot(meU && ((TD & K) != 0ull));                           \
        U &= ~(K | nR);                                                         \
        meU = (U >> lane) & 1;                                                  \
      }                                                                         \
      bool isk = (K >> lane) & 1;                                               \
      int rnk = __popcll(K & ((1ull << lane) - 1ull));                          \
      if (isk) klist[c_ & 3][rnk] = (unsigned char)lane;                        \
      if (lane == 0) keptw[c_] = K;                                             \
      kp3 = kp2; kp2 = kp1; kp1 = K;                                            \
      if (c_ + 2 < NW) {                                                        \
        TR0[PAR] = TRb[(c_ + 2) * 64 + lane];                                   \
        TR1[PAR] = TRb[N_BOXES + (c_ + 2) * 64 + lane];                         \
        TR2[PAR] = TRb[2 * N_BOXES + (c_ + 2) * 64 + lane];                     \
        TR3[PAR] = TRb[3 * N_BOXES + (c_ + 2) * 64 + lane];                     \
      }                                                                         \
    } else {                                                                    \
      /* COMMIT chunk c_-3 (loads issued region c_-2); words bb=c_+1 */         \
      if (c_ >= 3 && Kn[PAR] > 0) {                                             \
        const int wd0 = c_ + 1 + lane;                                          \
        const int wd1 = wd0 + 64;                                               \
        u64 v0 = 0, v1 = 0;                                                     \
        _Pragma("unroll")                                                       \
        for (int s = 0; s < NSLOT; ++s) { v0 |= H0[PAR][s]; v1 |= H1[PAR][s]; } \
        u32 kn = Kn[PAR];                                                       \
        if (kn > 7u * NSLOT) {                     /* rare overflow */          \
          const u32 cpb = (u32)(c_ - 3) * 64u;                                  \
          const unsigned char* kl = klist[(c_ + 1) & 3];                        \
          for (u32 r = 7u * NSLOT + (u32)grp; r < kn; r += 7u) {                \
            const u64* rp = RM + (size_t)(cpb + kl[r]) * NW;                    \
            if (wd0 < NW) v0 |= rp[wd0];                                        \
            if (wd1 < NW) v1 |= rp[wd1];                                        \
          }                                                                     \
        }                                                                       \
        if (wd0 < NW && v0) atomicOr((u64*)&rem32[2 * wd0], v0);                \
        if (wd1 < NW && v1) atomicOr((u64*)&rem32[2 * wd1], v1);                \
      }                                                                         \
      /* ISSUE chunk c_-1 (committed at region c_+2); words bb=c_+3 */          \
      {                                                                         \
        const int cp = c_ - 1;                                                  \
        if (cp >= 0 && c_ + 3 < NW) {                                           \
          u64 KW = keptw[cp];                                                   \
          u32 kn = (u32)__popcll(KW);                                           \
          Kn[PAR] = kn;                                                         \
          const int wi0 = c_ + 3 + lane;                                        \
          const int wi1 = wi0 + 64;                                             \
          const unsigned char* kl = klist[cp & 3];                              \
          const u32 cpb = (u32)cp * 64u;                                        \
          _Pragma("unroll")                                                     \
          for (int s = 0; s < NSLOT; ++s) {                                     \
            H0[PAR][s] = 0; H1[PAR][s] = 0;                                     \
            u32 r = (u32)(s * 7 + grp);            /* wave-uniform */           \
            if (r < kn) {                                                       \
              const u64* rp = RM + (size_t)(cpb + kl[r]) * NW;                  \
              if (wi0 < NW) H0[PAR][s] = rp[wi0];                               \
              if (wi1 < NW) H1[PAR][s] = rp[wi1];                               \
            }                                                                   \
          }                                                                     \
        } else Kn[PAR] = 0;                                                     \
      }                                                                         \
    }                                                                           \
    barrier_nodrain();                                                          \
  } while (0)

    for (int cc = 0; cc < NW; cc += 2) {
        REGION(cc, 0);
        REGION(cc + 1, 1);
    }
#undef REGION

    __syncthreads();
    if (tid < NW) keepw_g[tid] = keptw[tid];
}

// ---------------- Phase D: regression + masked output (full grid) ----------
__global__ void output_kernel(const float* __restrict__ bboxes,
                              const float* __restrict__ features,
                              const float* __restrict__ Wm, const float* __restrict__ bv,
                              const int* __restrict__ widthp, const int* __restrict__ heightp,
                              const u32* __restrict__ rank_of, const u64* __restrict__ keepw,
                              float* __restrict__ out) {
    int i = blockIdx.x * blockDim.x + threadIdx.x;
    if (i >= N_BOXES) return;
    u32 r = rank_of[i];
    float keep = (float)((keepw[r >> 6] >> (r & 63)) & 1ull);
    float z0 = bv[0], z1 = bv[1], z2 = bv[2], z3 = bv[3];
    #pragma unroll
    for (int m = 0; m < FEAT; ++m) {
        float f = features[i * FEAT + m];
        z0 += f * Wm[m * 4 + 0];
        z1 += f * Wm[m * 4 + 1];
        z2 += f * Wm[m * 4 + 2];
        z3 += f * Wm[m * 4 + 3];
    }
    float t0 = 1.0f / (1.0f + expf(-z0));
    float t1 = 1.0f / (1.0f + expf(-z1));
    float t2 = 1.0f / (1.0f + expf(-z2));
    float t3 = 1.0f / (1.0f + expf(-z3));
    float4 bx = ((const float4*)bboxes)[i];
    float ox = fmaxf(t0 * bx.z + bx.x, 0.0f);
    float oy = fmaxf(t1 * bx.w + bx.y, 0.0f);
    float ow = bx.z * expf(t2);
    float oh = bx.w * expf(t3);
    float sw = (float)(*widthp), sh = (float)(*heightp);
    float4 o;
    o.x = ox * sw * keep;
    o.y = oy * sh * keep;
    o.z = ow * sw * keep;
    o.w = oh * sh * keep;
    ((float4*)out)[i] = o;
}

extern "C" void kernel_launch(void* const* d_in, const int* in_sizes, int n_in,
                              void* d_out, int out_size, void* d_ws, size_t ws_size,
                              hipStream_t stream) {
    const float* bboxes   = (const float*)d_in[0];
    const float* scores   = (const float*)d_in[1];
    const float* features = (const float*)d_in[2];
    const float* Wm       = (const float*)d_in[3];
    const float* bv       = (const float*)d_in[4];
    const int*   widthp   = (const int*)d_in[5];
    const int*   heightp  = (const int*)d_in[6];
    float* out = (float*)d_out;

    char* ws = (char*)d_ws;
    u64* RM      = (u64*)ws;                                        // 8 MiB
    u64* TRb     = (u64*)(ws + (size_t)N_BOXES * NW * sizeof(u64)); // 256 KiB
    float* x1s   = (float*)((char*)TRb + (size_t)4 * N_BOXES * sizeof(u64));
    float* y1s   = x1s + N_BOXES;
    float* x2s   = y1s + N_BOXES;
    float* y2s   = x2s + N_BOXES;
    u32* rank_of = (u32*)(y2s + N_BOXES);
    u64* keepw   = (u64*)(rank_of + N_BOXES);

    rank_scatter_kernel<<<N_BOXES / 32, 256, 0, stream>>>(bboxes, scores,
                                                          x1s, y1s, x2s, y2s, rank_of);
    mask_kernel<<<dim3(NW, NW / 4), 256, 0, stream>>>(x1s, y1s, x2s, y2s, RM, TRb);
    nms_reduce_fused<<<1, 512, 0, stream>>>(RM, TRb, keepw);
    output_kernel<<<N_BOXES / 256, 256, 0, stream>>>(bboxes, features, Wm, bv,
                                                     widthp, heightp, rank_of, keepw, out);
}

// Round 12
// 131.280 us; speedup vs baseline: 1.5084x; 1.1535x over previous
//
#include <hip/hip_runtime.h>
#include <hip/hip_bf16.h>

#define N_BOXES 8192
#define NW 128            // number of 64-box chunks / 64-bit words per row
#define NREG 64           // regions (one chunk PAIR per region)
#define FEAT 10
#define NSLOT 4           // row slots per lane per chunk; 7 waves * 4 = 28 rows

typedef unsigned long long u64;
typedef unsigned int u32;

__device__ __forceinline__ void barrier_nodrain() {
    asm volatile("s_waitcnt lgkmcnt(0)" ::: "memory");
    __builtin_amdgcn_sched_barrier(0);
    __builtin_amdgcn_s_barrier();
    __builtin_amdgcn_sched_barrier(0);
    asm volatile("" ::: "memory");
}

// ---------------- Phase A: rank + scatter sorted boxes ----------------
__global__ void rank_scatter_kernel(const float* __restrict__ bboxes,
                                    const float* __restrict__ scores,
                                    float* __restrict__ x1s, float* __restrict__ y1s,
                                    float* __restrict__ x2s, float* __restrict__ y2s,
                                    u32* __restrict__ rank_of) {
    __shared__ float sc[N_BOXES];
    int tid = threadIdx.x;
    for (int t = 0; t < N_BOXES / 256; ++t)
        sc[tid + 256 * t] = scores[tid + 256 * t];
    __syncthreads();
    int k = tid >> 3;          // box slot 0..31
    int s = tid & 7;           // segment 0..7
    int i = blockIdx.x * 32 + k;
    float si = sc[i];
    int cnt = 0;
    const float4* sc4 = (const float4*)sc;
    int q0 = s * (N_BOXES / 32);
    #pragma unroll 4
    for (int q = q0; q < q0 + N_BOXES / 32; ++q) {
        float4 v = sc4[q];
        int j = 4 * q;
        cnt += (int)((v.x > si) || (v.x == si && j     > i));
        cnt += (int)((v.y > si) || (v.y == si && j + 1 > i));
        cnt += (int)((v.z > si) || (v.z == si && j + 2 > i));
        cnt += (int)((v.w > si) || (v.w == si && j + 3 > i));
    }
    cnt += __shfl_down(cnt, 4, 8);
    cnt += __shfl_down(cnt, 2, 8);
    cnt += __shfl_down(cnt, 1, 8);
    if (s == 0) {
        int r = cnt;
        float x = bboxes[4 * i + 0], y = bboxes[4 * i + 1];
        float w = bboxes[4 * i + 2], h = bboxes[4 * i + 3];
        float x2 = x + w, y2 = y + h;           // exact ref op order
        x1s[r] = x; y1s[r] = y; x2s[r] = x2; y2s[r] = y2;
        rank_of[i] = (u32)r;
    }
}

// ---------------- Phase B: suppression bitmask matrix ----------------
// Row-major: RM[i*NW + cj] = word over j in chunk cj of sup(i->j) (j>i).
// TRb[d*N + j] (d=0..5) = word over i in chunk (chunk(j)-d) of sup(i->j).
__global__ void __launch_bounds__(256) mask_kernel(
        const float* __restrict__ x1s, const float* __restrict__ y1s,
        const float* __restrict__ x2s, const float* __restrict__ y2s,
        u64* __restrict__ RM, u64* __restrict__ TRb) {
    int wv = threadIdx.x >> 6, lane = threadIdx.x & 63;
    int ci = blockIdx.x;
    int cj = blockIdx.y * 4 + wv;
    if (cj < ci) return;
    __shared__ float S[4][4][64];
    int d = cj - ci;
    int ig0 = ci * 64, jg0 = cj * 64;
    if (d <= 5) {
        // ballot path: lanes = columns j; i-chunk staged in LDS
        S[wv][0][lane] = x1s[ig0 + lane];
        S[wv][1][lane] = y1s[ig0 + lane];
        S[wv][2][lane] = x2s[ig0 + lane];
        S[wv][3][lane] = y2s[ig0 + lane];
        int jg = jg0 + lane;
        float jx1 = x1s[jg], jy1 = y1s[jg], jx2 = x2s[jg], jy2 = y2s[jg];
        float jar = (jx2 - jx1) * (jy2 - jy1);   // bit-identical to ref area
        u64 my = 0, cw = 0;
        for (int ip = 0; ip < 64; ++ip) {
            float ax1 = S[wv][0][ip], ay1 = S[wv][1][ip];
            float ax2 = S[wv][2][ip], ay2 = S[wv][3][ip];
            float aar = (ax2 - ax1) * (ay2 - ay1);
            float xx1 = fmaxf(ax1, jx1);
            float yy1 = fmaxf(ay1, jy1);
            float xx2 = fminf(ax2, jx2);
            float yy2 = fminf(ay2, jy2);
            float iw = fmaxf(xx2 - xx1, 0.0f);
            float ih = fmaxf(yy2 - yy1, 0.0f);
            float inter = iw * ih;
            float uni = aar + jar - inter;
            float iou = __fdiv_rn(inter, uni);   // IEEE-exact like numpy
            bool sup = (iou > 0.5f) && (jg > ig0 + ip);
            u64 w = __ballot(sup);
            if (lane == ip) my = w;
            cw |= sup ? (1ull << ip) : 0ull;
        }
        RM[(size_t)(ig0 + lane) * NW + cj] = my;
        TRb[(size_t)d * N_BOXES + jg] = cw;
    } else {
        // direct path: lanes = rows i; j-chunk staged in LDS
        S[wv][0][lane] = x1s[jg0 + lane];
        S[wv][1][lane] = y1s[jg0 + lane];
        S[wv][2][lane] = x2s[jg0 + lane];
        S[wv][3][lane] = y2s[jg0 + lane];
        int ig = ig0 + lane;
        float ix1 = x1s[ig], iy1 = y1s[ig], ix2 = x2s[ig], iy2 = y2s[ig];
        float iar = (ix2 - ix1) * (iy2 - iy1);
        u64 my = 0;
        for (int jp = 0; jp < 64; ++jp) {
            float jx1 = S[wv][0][jp], jy1 = S[wv][1][jp];
            float jx2 = S[wv][2][jp], jy2 = S[wv][3][jp];
            float jar = (jx2 - jx1) * (jy2 - jy1);
            float xx1 = fmaxf(ix1, jx1);
            float yy1 = fmaxf(iy1, jy1);
            float xx2 = fminf(ix2, jx2);
            float yy2 = fminf(iy2, jy2);
            float iw = fmaxf(xx2 - xx1, 0.0f);
            float ih = fmaxf(yy2 - yy1, 0.0f);
            float inter = iw * ih;
            float uni = iar + jar - inter;
            float iou = __fdiv_rn(inter, uni);
            bool sup = (iou > 0.5f);             // cj>ci+5 => j>i always
            my |= sup ? (1ull << jp) : 0ull;
        }
        RM[(size_t)ig * NW + cj] = my;
    }
}

// ---------------- Phase C: greedy reduce (1 block), chunk-pair regions -----
// Region q resolves chunks c0=2q, c1=2q+1 (two fixpoints; c1 folds c0's
// fresh K via the d1 plane). Folds: even d1..d4, odd fresh+d2..d5; rem32
// base needs only chunks <= 2q-5 (pairs <= q-3, committed at region <= q-1).
// Workers ISSUE pair q-1's kept rows at region q (words >= 2q+3) and COMMIT
// at region q+1 (words >= 2q+3 == that region's 2q'+1); word 2q+1 tearing is
// benign (bits duplicated by d4/d5 folds).
__global__ void __launch_bounds__(512) nms_reduce(
        const u64* __restrict__ RM, const u64* __restrict__ TRb,
        u64* __restrict__ keepw_g) {
    __shared__ __align__(8) u32 rem32[NW * 2];
    __shared__ u64 keptw[NW];
    __shared__ unsigned char klA[4][64], klB[4][64];

    const int tid = threadIdx.x;
    const int wv = tid >> 6, lane = tid & 63;
    const int grp = wv - 1;                       // 0..6 for workers

    if (tid < NW * 2) rem32[tid] = 0;

    u64 TDe[2], T1e[2], T2e[2], T3e[2], T4e[2];
    u64 TDo[2], T1o[2], T2o[2], T3o[2], T4o[2], T5o[2];
    u64 kp1 = 0, kp2 = 0, kp3 = 0, kp4 = 0;
    if (wv == 0) {     // region 0 set (chunks 0,1); unwritten planes masked by kp=0
        TDe[0] = TRb[lane];
        T1e[0] = TRb[N_BOXES + lane];
        T2e[0] = TRb[2 * N_BOXES + lane];
        T3e[0] = TRb[3 * N_BOXES + lane];
        T4e[0] = TRb[4 * N_BOXES + lane];
        TDo[0] = TRb[64 + lane];
        T1o[0] = TRb[N_BOXES + 64 + lane];        // d1[chunk1]: valid (fresh fold)
        T2o[0] = TRb[2 * N_BOXES + 64 + lane];
        T3o[0] = TRb[3 * N_BOXES + 64 + lane];
        T4o[0] = TRb[4 * N_BOXES + 64 + lane];
        T5o[0] = TRb[5 * N_BOXES + 64 + lane];
    }
    u64 HA0[NSLOT], HA1[NSLOT], HB0[NSLOT], HB1[NSLOT];
    u32 KnA = 0, KnB = 0;
    __syncthreads();

#define FIXPOINT(TD, RIN, KOUT)                                                 \
    {                                                                           \
      u64 K = 0, U = ~(RIN);                                                    \
      bool meU = (U >> lane) & 1;                                               \
      while (U) {                                                               \
        u64 UK = U | K;                                                         \
        u64 nK = __ballot(meU && (((TD) & UK) == 0ull));                        \
        K |= nK;                                                                \
        u64 nR = __ballot(meU && (((TD) & K) != 0ull));                         \
        U &= ~(K | nR);                                                         \
        meU = (U >> lane) & 1;                                                  \
      }                                                                         \
      (KOUT) = K;                                                               \
    }

#define REGION(Q, PAR)                                                          \
  do {                                                                          \
    const int q_ = (Q);                                                         \
    const int c0 = 2 * q_, c1 = 2 * q_ + 1;                                     \
    if (wv == 0) {                                                              \
      if (q_ + 1 < NREG) {            /* prefetch next region's TR set */       \
        const int n0 = (c0 + 2) * 64 + lane, n1 = n0 + 64;                      \
        TDe[PAR ^ 1] = TRb[n0];                                                 \
        T1e[PAR ^ 1] = TRb[N_BOXES + n0];                                       \
        T2e[PAR ^ 1] = TRb[2 * N_BOXES + n0];                                   \
        T3e[PAR ^ 1] = TRb[3 * N_BOXES + n0];                                   \
        T4e[PAR ^ 1] = TRb[4 * N_BOXES + n0];                                   \
        TDo[PAR ^ 1] = TRb[n1];                                                 \
        T1o[PAR ^ 1] = TRb[N_BOXES + n1];                                       \
        T2o[PAR ^ 1] = TRb[2 * N_BOXES + n1];                                   \
        T3o[PAR ^ 1] = TRb[3 * N_BOXES + n1];                                   \
        T4o[PAR ^ 1] = TRb[4 * N_BOXES + n1];                                   \
        T5o[PAR ^ 1] = TRb[5 * N_BOXES + n1];                                   \
      }                                                                         \
      u64 K0, K1;                                                               \
      {                                                                         \
        u64 base0 = *(const u64*)&rem32[2 * c0];                                \
        u64 R0 = base0 | __ballot(((T1e[PAR] & kp1) | (T2e[PAR] & kp2) |        \
                                   (T3e[PAR] & kp3) | (T4e[PAR] & kp4)) != 0ull);\
        FIXPOINT(TDe[PAR], R0, K0);                                             \
        bool isk = (K0 >> lane) & 1;                                            \
        int rnk = __popcll(K0 & ((1ull << lane) - 1ull));                       \
        if (isk) klA[q_ & 3][rnk] = (unsigned char)lane;                        \
        if (lane == 0) keptw[c0] = K0;                                          \
      }                                                                         \
      {                                                                         \
        u64 base1 = *(const u64*)&rem32[2 * c1];                                \
        u64 R1 = base1 | __ballot(((T1o[PAR] & K0)  | (T2o[PAR] & kp1) |        \
                                   (T3o[PAR] & kp2) | (T4o[PAR] & kp3) |        \
                                   (T5o[PAR] & kp4)) != 0ull);                  \
        FIXPOINT(TDo[PAR], R1, K1);                                             \
        bool isk = (K1 >> lane) & 1;                                            \
        int rnk = __popcll(K1 & ((1ull << lane) - 1ull));                       \
        if (isk) klB[q_ & 3][rnk] = (unsigned char)lane;                        \
        if (lane == 0) keptw[c1] = K1;                                          \
      }                                                                         \
      kp4 = kp2; kp3 = kp1; kp2 = K0; kp1 = K1;                                 \
    } else {                                                                    \
      /* COMMIT pair q_-2 (issued last region); words >= 2q+1 */                \
      if (q_ >= 2 && (KnA | KnB)) {                                             \
        const int wd0 = 2 * q_ + 1 + lane;                                      \
        const int wd1 = wd0 + 64;                                               \
        u64 v0 = 0, v1 = 0;                                                     \
        _Pragma("unroll")                                                       \
        for (int s = 0; s < NSLOT; ++s) {                                       \
          v0 |= HA0[s] | HB0[s];                                                \
          v1 |= HA1[s] | HB1[s];                                                \
        }                                                                       \
        if (KnA > 7u * NSLOT) {                    /* rare overflow */          \
          const u32 cpb = (u32)(2 * q_ - 4) * 64u;                              \
          const unsigned char* kl = klA[(q_ - 2) & 3];                          \
          for (u32 r = 7u * NSLOT + (u32)grp; r < KnA; r += 7u) {               \
            const u64* rp = RM + (size_t)(cpb + kl[r]) * NW;                    \
            if (wd0 < NW) v0 |= rp[wd0];                                        \
            if (wd1 < NW) v1 |= rp[wd1];                                        \
          }                                                                     \
        }                                                                       \
        if (KnB > 7u * NSLOT) {                                                 \
          const u32 cpb = (u32)(2 * q_ - 3) * 64u;                              \
          const unsigned char* kl = klB[(q_ - 2) & 3];                          \
          for (u32 r = 7u * NSLOT + (u32)grp; r < KnB; r += 7u) {               \
            const u64* rp = RM + (size_t)(cpb + kl[r]) * NW;                    \
            if (wd0 < NW) v0 |= rp[wd0];                                        \
            if (wd1 < NW) v1 |= rp[wd1];                                        \
          }                                                                     \
        }                                                                       \
        if (wd0 < NW && v0) atomicOr((u64*)&rem32[2 * wd0], v0);                \
        if (wd1 < NW && v1) atomicOr((u64*)&rem32[2 * wd1], v1);                \
      }                                                                         \
      /* ISSUE pair q_-1 (committed next region); words >= 2q+3 */              \
      {                                                                         \
        const int ib = 2 * q_ + 3;                                              \
        if (q_ >= 1 && ib < NW) {                                               \
          const u32 cA = (u32)(2 * q_ - 2) * 64u, cB = cA + 64u;                \
          KnA = (u32)__popcll(keptw[2 * q_ - 2]);                               \
          KnB = (u32)__popcll(keptw[2 * q_ - 1]);                               \
          const int wi0 = ib + lane;                                            \
          const int wi1 = wi0 + 64;                                             \
          const unsigned char* kla = klA[(q_ - 1) & 3];                         \
          const unsigned char* klb = klB[(q_ - 1) & 3];                         \
          _Pragma("unroll")                                                     \
          for (int s = 0; s < NSLOT; ++s) {                                     \
            HA0[s] = 0; HA1[s] = 0; HB0[s] = 0; HB1[s] = 0;                     \
            u32 r = (u32)(s * 7 + grp);            /* wave-uniform */           \
            if (r < KnA) {                                                      \
              const u64* rp = RM + (size_t)(cA + kla[r]) * NW;                  \
              if (wi0 < NW) HA0[s] = rp[wi0];                                   \
              if (wi1 < NW) HA1[s] = rp[wi1];                                   \
            }                                                                   \
            if (r < KnB) {                                                      \
              const u64* rp = RM + (size_t)(cB + klb[r]) * NW;                  \
              if (wi0 < NW) HB0[s] = rp[wi0];                                   \
              if (wi1 < NW) HB1[s] = rp[wi1];                                   \
            }                                                                   \
          }                                                                     \
        } else { KnA = 0; KnB = 0; }                                            \
      }                                                                         \
    }                                                                           \
    barrier_nodrain();                                                          \
  } while (0)

    for (int qq = 0; qq < NREG; qq += 2) {
        REGION(qq, 0);
        REGION(qq + 1, 1);
    }
#undef REGION
#undef FIXPOINT

    __syncthreads();
    if (tid < NW) keepw_g[tid] = keptw[tid];
}

// ---------------- Phase D: regression + masked output (full grid) ----------
__global__ void output_kernel(const float* __restrict__ bboxes,
                              const float* __restrict__ features,
                              const float* __restrict__ Wm, const float* __restrict__ bv,
                              const int* __restrict__ widthp, const int* __restrict__ heightp,
                              const u32* __restrict__ rank_of, const u64* __restrict__ keepw,
                              float* __restrict__ out) {
    int i = blockIdx.x * blockDim.x + threadIdx.x;
    if (i >= N_BOXES) return;
    u32 r = rank_of[i];
    float keep = (float)((keepw[r >> 6] >> (r & 63)) & 1ull);
    float z0 = bv[0], z1 = bv[1], z2 = bv[2], z3 = bv[3];
    #pragma unroll
    for (int m = 0; m < FEAT; ++m) {
        float f = features[i * FEAT + m];
        z0 += f * Wm[m * 4 + 0];
        z1 += f * Wm[m * 4 + 1];
        z2 += f * Wm[m * 4 + 2];
        z3 += f * Wm[m * 4 + 3];
    }
    float t0 = 1.0f / (1.0f + expf(-z0));
    float t1 = 1.0f / (1.0f + expf(-z1));
    float t2 = 1.0f / (1.0f + expf(-z2));
    float t3 = 1.0f / (1.0f + expf(-z3));
    float4 bx = ((const float4*)bboxes)[i];
    float ox = fmaxf(t0 * bx.z + bx.x, 0.0f);
    float oy = fmaxf(t1 * bx.w + bx.y, 0.0f);
    float ow = bx.z * expf(t2);
    float oh = bx.w * expf(t3);
    float sw = (float)(*widthp), sh = (float)(*heightp);
    float4 o;
    o.x = ox * sw * keep;
    o.y = oy * sh * keep;
    o.z = ow * sw * keep;
    o.w = oh * sh * keep;
    ((float4*)out)[i] = o;
}

extern "C" void kernel_launch(void* const* d_in, const int* in_sizes, int n_in,
                              void* d_out, int out_size, void* d_ws, size_t ws_size,
                              hipStream_t stream) {
    const float* bboxes   = (const float*)d_in[0];
    const float* scores   = (const float*)d_in[1];
    const float* features = (const float*)d_in[2];
    const float* Wm       = (const float*)d_in[3];
    const float* bv       = (const float*)d_in[4];
    const int*   widthp   = (const int*)d_in[5];
    const int*   heightp  = (const int*)d_in[6];
    float* out = (float*)d_out;

    char* ws = (char*)d_ws;
    u64* RM      = (u64*)ws;                                        // 8 MiB
    u64* TRb     = (u64*)(ws + (size_t)N_BOXES * NW * sizeof(u64)); // 384 KiB (6 planes)
    float* x1s   = (float*)((char*)TRb + (size_t)6 * N_BOXES * sizeof(u64));
    float* y1s   = x1s + N_BOXES;
    float* x2s   = y1s + N_BOXES;
    float* y2s   = x2s + N_BOXES;
    u32* rank_of = (u32*)(y2s + N_BOXES);
    u64* keepw   = (u64*)(rank_of + N_BOXES);

    rank_scatter_kernel<<<N_BOXES / 32, 256, 0, stream>>>(bboxes, scores,
                                                          x1s, y1s, x2s, y2s, rank_of);
    mask_kernel<<<dim3(NW, NW / 4), 256, 0, stream>>>(x1s, y1s, x2s, y2s, RM, TRb);
    nms_reduce<<<1, 512, 0, stream>>>(RM, TRb, keepw);
    output_kernel<<<N_BOXES / 256, 256, 0, stream>>>(bboxes, features, Wm, bv,
                                                     widthp, heightp, rank_of, keepw, out);
}